// Round 3
// baseline (543.825 us; speedup 1.0000x reference)
//
#include <hip/hip_runtime.h>
#include <hip/hip_bf16.h>

#define NB   16384
#define NE   64
#define DIN  128
#define DOUT 128

// ws layout in 4-byte words (total ~795 KB)
#define WS_COUNTS   0        // 64
#define WS_BASE     64       // 64
#define WS_CURSOR   128      // 64
#define WS_NWORK    192      // 1
#define WS_WORK     256      // <= 832
#define WS_PICKED   2048     // 3*NB
#define WS_PW       51200    // 3*NB
#define WS_PAIRROW  100352   // 3*NB
#define WS_PAIRW    149504   // 3*NB
#define MAX_WORK    832      // sum_e ceil(n_e/64) <= 3*NB/64 + 64 = 832

__global__ __launch_bounds__(64) void k0_init(int* __restrict__ wsI) {
  if (threadIdx.x < NE) wsI[WS_COUNTS + threadIdx.x] = 0;
}

__global__ __launch_bounds__(256) void k1_route(
    const float* __restrict__ x, const float* __restrict__ dsc,
    const float* __restrict__ cent, float* __restrict__ out,
    int* __restrict__ wsI, float* __restrict__ wsF) {
  __shared__ float cl[NE][132];   // pad 132: 16B-aligned rows, banks (4e+d)%32
  __shared__ float xl[16][132];
  const int tid = threadIdx.x;
  const int row0 = blockIdx.x * 16;

  // stage centroids (64x128 f32 = 2048 float4)
  const float4* c4 = (const float4*)cent;
  #pragma unroll
  for (int k = 0; k < 8; ++k) {
    int idx = tid + k * 256;
    int e = idx >> 5, dc = idx & 31;
    *(float4*)&cl[e][dc * 4] = c4[idx];
  }
  // stage 16 rows of x (512 float4)
  const float4* x4 = (const float4*)x + row0 * 32;
  #pragma unroll
  for (int k = 0; k < 2; ++k) {
    int idx = tid + k * 256;
    int r = idx >> 5, dc = idx & 31;
    *(float4*)&xl[r][dc * 4] = x4[idx];
  }
  // zero this block's slice of out (kernel4 accumulates atomically)
  float4* o4 = (float4*)out + row0 * 32;
  float4 z; z.x = z.y = z.z = z.w = 0.f;
  #pragma unroll
  for (int k = 0; k < 2; ++k) o4[tid + k * 256] = z;
  __syncthreads();

  const int lane = tid & 63, wv = tid >> 6;
  const float ds = dsc[0];

  for (int rr = wv; rr < 16; rr += 4) {
    // distance_sq for expert `lane`, replicating numpy pairwise mean over 128:
    // 8 accumulators r[j] += sq[8i+j], then ((r0+r1)+(r2+r3))+((r4+r5)+(r6+r7))
    float4 r0 = {0.f, 0.f, 0.f, 0.f}, r1 = {0.f, 0.f, 0.f, 0.f};
    {
      #pragma clang fp contract(off)
      for (int i = 0; i < 16; ++i) {
        float4 xa = *(const float4*)&xl[rr][i * 8];
        float4 xb = *(const float4*)&xl[rr][i * 8 + 4];
        float4 ca = *(const float4*)&cl[lane][i * 8];
        float4 cb = *(const float4*)&cl[lane][i * 8 + 4];
        float t0 = ds * (xa.x - ca.x), t1 = ds * (xa.y - ca.y);
        float t2 = ds * (xa.z - ca.z), t3 = ds * (xa.w - ca.w);
        float u0 = ds * (xb.x - cb.x), u1 = ds * (xb.y - cb.y);
        float u2 = ds * (xb.z - cb.z), u3 = ds * (xb.w - cb.w);
        r0.x += t0 * t0; r0.y += t1 * t1; r0.z += t2 * t2; r0.w += t3 * t3;
        r1.x += u0 * u0; r1.y += u1 * u1; r1.z += u2 * u2; r1.w += u3 * u3;
      }
    }
    float s = ((r0.x + r0.y) + (r0.z + r0.w)) + ((r1.x + r1.y) + (r1.z + r1.w));
    float dist = s / 128.0f;

    // top-3 smallest distance across 64 lanes, ties -> lower index (jax top_k)
    int imin[3];
    float dcur = dist; int icur = lane;
    #pragma unroll
    for (int k = 0; k < 3; ++k) {
      float bd = dcur; int bi = icur;
      #pragma unroll
      for (int off = 32; off; off >>= 1) {
        float od = __shfl_xor(bd, off, 64);
        int   oi = __shfl_xor(bi, off, 64);
        if (od < bd || (od == bd && oi < bi)) { bd = od; bi = oi; }
      }
      imin[k] = bi;
      if (icur == bi) dcur = INFINITY;  // remove winner
    }

    // weights from experts 0,1,2 distances (reference quirk: [:, :es])
    float d0 = __shfl(dist, 0, 64);
    float d1 = __shfl(dist, 1, 64);
    float d2 = __shfl(dist, 2, 64);
    float w0 = 1.f / (1.f + d0), w1 = 1.f / (1.f + d1), w2 = 1.f / (1.f + d2);
    float sw = (w0 + w1) + w2;
    w0 /= sw; w1 /= sw; w2 /= sw;

    int row = row0 + rr;
    if (lane < 3) {
      float w = (lane == 0) ? w0 : ((lane == 1) ? w1 : w2);
      int p = imin[lane];
      wsI[WS_PICKED + row * 3 + lane] = p;
      wsF[WS_PW + row * 3 + lane] = w;
      atomicAdd(&wsI[WS_COUNTS + p], 1);
    }
  }
}

__global__ __launch_bounds__(64) void k2_scan(int* __restrict__ wsI) {
  if (threadIdx.x == 0) {
    int acc = 0;
    for (int e = 0; e < NE; ++e) {
      wsI[WS_BASE + e] = acc;
      wsI[WS_CURSOR + e] = acc;
      acc += wsI[WS_COUNTS + e];
    }
    int wn = 0;
    for (int e = 0; e < NE; ++e) {
      int c = wsI[WS_COUNTS + e];
      int nt = (c + 63) >> 6;
      for (int t = 0; t < nt; ++t) wsI[WS_WORK + wn++] = (e << 16) | t;
    }
    wsI[WS_NWORK] = wn;
  }
}

__global__ __launch_bounds__(256) void k3_scatter(int* __restrict__ wsI,
                                                  float* __restrict__ wsF) {
  int p = blockIdx.x * 256 + threadIdx.x;
  if (p < 3 * NB) {
    int e = wsI[WS_PICKED + p];
    float w = wsF[WS_PW + p];
    int pos = atomicAdd(&wsI[WS_CURSOR + e], 1);
    wsI[WS_PAIRROW + pos] = p / 3;   // row
    wsF[WS_PAIRW + pos] = w;
  }
}

// One block per (expert, 64-row tile). 256 threads: thread = (tr=tid&15, tc=tid>>4)
// computes 4 rows x 8 cols. x tile staged transposed in LDS; W[e] in 32-d chunks.
__global__ __launch_bounds__(256) void k4_gemm(
    const float* __restrict__ x, const float* __restrict__ W,
    const float* __restrict__ bias, const int* __restrict__ wsI,
    const float* __restrict__ wsF, float* __restrict__ out) {
  __shared__ float xT[DIN][68];     // [d][r], pad 68 (16B-aligned, banks spread)
  __shared__ float Wl[32][DOUT];
  __shared__ int   rowsl[64];
  __shared__ float wl[64];

  const int nwork = wsI[WS_NWORK];
  const int bid = blockIdx.x;
  if (bid >= nwork) return;
  const int wk = wsI[WS_WORK + bid];
  const int e = wk >> 16, t = wk & 0xffff;
  const int cnt = wsI[WS_COUNTS + e];
  const int srcb = wsI[WS_BASE + e] + t * 64;
  const int m = min(64, cnt - t * 64);
  const int tid = threadIdx.x;

  if (tid < 64) {
    int src = srcb + ((tid < m) ? tid : 0);  // clamp pad lanes to a valid entry
    rowsl[tid] = wsI[WS_PAIRROW + src];
    wl[tid] = (tid < m) ? wsF[WS_PAIRW + srcb + tid] : 0.f;
  }
  __syncthreads();

  // stage x transposed: 4 threads per row, 32 d's each
  {
    int r = tid >> 2;
    int d0 = (tid & 3) * 32;
    const float* xr = x + (long)rowsl[r] * DIN + d0;
    #pragma unroll
    for (int k = 0; k < 32; k += 4) {
      float4 v = *(const float4*)(xr + k);
      xT[d0 + k + 0][r] = v.x;
      xT[d0 + k + 1][r] = v.y;
      xT[d0 + k + 2][r] = v.z;
      xT[d0 + k + 3][r] = v.w;
    }
  }

  float acc[4][8];
  #pragma unroll
  for (int i = 0; i < 4; ++i)
    #pragma unroll
    for (int j = 0; j < 8; ++j) acc[i][j] = 0.f;

  const int tr = tid & 15, tc = tid >> 4;

  for (int dc = 0; dc < DIN; dc += 32) {
    __syncthreads();  // first iter: covers xT/rowsl staging; later: protect Wl reuse
    const float4* Wg = (const float4*)(W + (long)e * DIN * DOUT + dc * DOUT);
    float4* Wl4 = (float4*)&Wl[0][0];
    #pragma unroll
    for (int k = 0; k < 4; ++k) Wl4[tid + k * 256] = Wg[tid + k * 256];
    __syncthreads();
    #pragma unroll 8
    for (int dd = 0; dd < 32; ++dd) {
      float4 xv = *(const float4*)&xT[dc + dd][tr * 4];
      float4 wa = *(const float4*)&Wl[dd][tc * 8];
      float4 wb = *(const float4*)&Wl[dd][tc * 8 + 4];
      float xs[4] = {xv.x, xv.y, xv.z, xv.w};
      float ws8[8] = {wa.x, wa.y, wa.z, wa.w, wb.x, wb.y, wb.z, wb.w};
      #pragma unroll
      for (int i = 0; i < 4; ++i)
        #pragma unroll
        for (int j = 0; j < 8; ++j) acc[i][j] += xs[i] * ws8[j];
    }
  }

  #pragma unroll
  for (int i = 0; i < 4; ++i) {
    int r = tr * 4 + i;
    if (r < m) {
      int row = rowsl[r];
      float w = wl[r];
      float* op = out + (long)row * DOUT + tc * 8;
      const float* bp = bias + (long)e * DOUT + tc * 8;
      #pragma unroll
      for (int j = 0; j < 8; ++j) atomicAdd(&op[j], w * (acc[i][j] + bp[j]));
    }
  }
}

extern "C" void kernel_launch(void* const* d_in, const int* in_sizes, int n_in,
                              void* d_out, int out_size, void* d_ws, size_t ws_size,
                              hipStream_t stream) {
  const float* x    = (const float*)d_in[0];
  const float* dsc  = (const float*)d_in[1];
  const float* cent = (const float*)d_in[2];
  const float* W    = (const float*)d_in[3];
  const float* bias = (const float*)d_in[4];
  float* out = (float*)d_out;
  int* wsI = (int*)d_ws;
  float* wsF = (float*)d_ws;

  hipLaunchKernelGGL(k0_init,    dim3(1),           dim3(64),  0, stream, wsI);
  hipLaunchKernelGGL(k1_route,   dim3(NB / 16),     dim3(256), 0, stream, x, dsc, cent, out, wsI, wsF);
  hipLaunchKernelGGL(k2_scan,    dim3(1),           dim3(64),  0, stream, wsI);
  hipLaunchKernelGGL(k3_scatter, dim3(3 * NB / 256), dim3(256), 0, stream, wsI, wsF);
  hipLaunchKernelGGL(k4_gemm,    dim3(MAX_WORK),    dim3(256), 0, stream, x, W, bias, wsI, wsF, out);
}

// Round 4
// 371.373 us; speedup vs baseline: 1.4644x; 1.4644x over previous
//
#include <hip/hip_runtime.h>
#include <hip/hip_bf16.h>

#define NB   16384
#define NE   64
#define DIN  128
#define DOUT 128

// ws layout in 4-byte words
#define WS_COUNTS   0        // 64
#define WS_BASE     64       // 64
#define WS_CURSOR   128      // 64
#define WS_NWORK    192      // 1
#define WS_WORK     256      // <= 832
#define WS_PICKED   2048     // 3*NB
#define WS_PW       51200    // 3*NB
#define WS_PAIRROW  100352   // 3*NB
#define WS_PAIRW    149504   // 3*NB
#define WS_PAIRP    198656   // 3*NB  (pair index p = row*3+slot, for slot path)
#define WS_SLOT     247808   // 3*NB*128 floats (slot buffer, slot path only)
#define MAX_WORK    832      // sum_e ceil(n_e/64) <= 3*NB/64 + 63 < 832

__global__ __launch_bounds__(64) void k0_init(int* __restrict__ wsI) {
  if (threadIdx.x < NE) wsI[WS_COUNTS + threadIdx.x] = 0;
}

__global__ __launch_bounds__(256) void k1_route(
    const float* __restrict__ x, const float* __restrict__ dsc,
    const float* __restrict__ cent, float* __restrict__ out,
    int* __restrict__ wsI, float* __restrict__ wsF, int zero_out) {
  __shared__ float cl[NE][132];
  __shared__ float xl[16][132];
  const int tid = threadIdx.x;
  const int row0 = blockIdx.x * 16;

  const float4* c4 = (const float4*)cent;
  #pragma unroll
  for (int k = 0; k < 8; ++k) {
    int idx = tid + k * 256;
    int e = idx >> 5, dc = idx & 31;
    *(float4*)&cl[e][dc * 4] = c4[idx];
  }
  const float4* x4 = (const float4*)x + row0 * 32;
  #pragma unroll
  for (int k = 0; k < 2; ++k) {
    int idx = tid + k * 256;
    int r = idx >> 5, dc = idx & 31;
    *(float4*)&xl[r][dc * 4] = x4[idx];
  }
  if (zero_out) {  // atomic-fallback path only
    float4* o4 = (float4*)out + row0 * 32;
    float4 z; z.x = z.y = z.z = z.w = 0.f;
    #pragma unroll
    for (int k = 0; k < 2; ++k) o4[tid + k * 256] = z;
  }
  __syncthreads();

  const int lane = tid & 63, wv = tid >> 6;
  const float ds = dsc[0];

  for (int rr = wv; rr < 16; rr += 4) {
    // distance_sq for expert `lane`, replicating numpy pairwise mean over 128:
    // 8 accumulators r[j] += sq[8i+j], then ((r0+r1)+(r2+r3))+((r4+r5)+(r6+r7))
    float4 r0 = {0.f, 0.f, 0.f, 0.f}, r1 = {0.f, 0.f, 0.f, 0.f};
    {
      #pragma clang fp contract(off)
      for (int i = 0; i < 16; ++i) {
        float4 xa = *(const float4*)&xl[rr][i * 8];
        float4 xb = *(const float4*)&xl[rr][i * 8 + 4];
        float4 ca = *(const float4*)&cl[lane][i * 8];
        float4 cb = *(const float4*)&cl[lane][i * 8 + 4];
        float t0 = ds * (xa.x - ca.x), t1 = ds * (xa.y - ca.y);
        float t2 = ds * (xa.z - ca.z), t3 = ds * (xa.w - ca.w);
        float u0 = ds * (xb.x - cb.x), u1 = ds * (xb.y - cb.y);
        float u2 = ds * (xb.z - cb.z), u3 = ds * (xb.w - cb.w);
        r0.x += t0 * t0; r0.y += t1 * t1; r0.z += t2 * t2; r0.w += t3 * t3;
        r1.x += u0 * u0; r1.y += u1 * u1; r1.z += u2 * u2; r1.w += u3 * u3;
      }
    }
    float s = ((r0.x + r0.y) + (r0.z + r0.w)) + ((r1.x + r1.y) + (r1.z + r1.w));
    float dist = s / 128.0f;

    // top-3 smallest across 64 lanes, ties -> lower index (jax top_k)
    int imin[3];
    float dcur = dist; int icur = lane;
    #pragma unroll
    for (int k = 0; k < 3; ++k) {
      float bd = dcur; int bi = icur;
      #pragma unroll
      for (int off = 32; off; off >>= 1) {
        float od = __shfl_xor(bd, off, 64);
        int   oi = __shfl_xor(bi, off, 64);
        if (od < bd || (od == bd && oi < bi)) { bd = od; bi = oi; }
      }
      imin[k] = bi;
      if (icur == bi) dcur = INFINITY;
    }

    // weights from experts 0,1,2 distances (reference quirk: [:, :es])
    float d0 = __shfl(dist, 0, 64);
    float d1 = __shfl(dist, 1, 64);
    float d2 = __shfl(dist, 2, 64);
    float w0 = 1.f / (1.f + d0), w1 = 1.f / (1.f + d1), w2 = 1.f / (1.f + d2);
    float sw = (w0 + w1) + w2;
    w0 /= sw; w1 /= sw; w2 /= sw;

    int row = row0 + rr;
    if (lane < 3) {
      float w = (lane == 0) ? w0 : ((lane == 1) ? w1 : w2);
      int p = imin[lane];
      wsI[WS_PICKED + row * 3 + lane] = p;
      wsF[WS_PW + row * 3 + lane] = w;
      atomicAdd(&wsI[WS_COUNTS + p], 1);
    }
  }
}

// 1-wave parallel scan (replaces the serial single-thread version: it was
// ~hundreds of µs of dependent global round-trips)
__global__ __launch_bounds__(64) void k2_scan(int* __restrict__ wsI) {
  const int lane = threadIdx.x;
  int cnt = wsI[WS_COUNTS + lane];
  // inclusive prefix sum of counts
  int xs = cnt;
  #pragma unroll
  for (int off = 1; off < 64; off <<= 1) {
    int y = __shfl_up(xs, off, 64);
    if (lane >= off) xs += y;
  }
  int excl = xs - cnt;
  wsI[WS_BASE + lane]   = excl;
  wsI[WS_CURSOR + lane] = excl;
  // inclusive prefix sum of tile counts
  int nt = (cnt + 63) >> 6;
  int ts = nt;
  #pragma unroll
  for (int off = 1; off < 64; off <<= 1) {
    int y = __shfl_up(ts, off, 64);
    if (lane >= off) ts += y;
  }
  int texcl = ts - nt;
  for (int t = 0; t < nt; ++t) wsI[WS_WORK + texcl + t] = (lane << 16) | t;
  if (lane == 63) wsI[WS_NWORK] = ts;
}

__global__ __launch_bounds__(256) void k3_scatter(int* __restrict__ wsI,
                                                  float* __restrict__ wsF) {
  int p = blockIdx.x * 256 + threadIdx.x;
  if (p < 3 * NB) {
    int e = wsI[WS_PICKED + p];
    float w = wsF[WS_PW + p];
    int pos = atomicAdd(&wsI[WS_CURSOR + e], 1);
    wsI[WS_PAIRROW + pos] = p / 3;   // row (for x gather)
    wsI[WS_PAIRP + pos]   = p;       // pair index (for slot write)
    wsF[WS_PAIRW + pos]   = w;
  }
}

// One block per (expert, 64-row tile). SLOT=1: write weighted result to
// slotbuf[p] (atomic-free). SLOT=0: atomicAdd into out (fallback).
template <int SLOT>
__global__ __launch_bounds__(256) void k4_gemm(
    const float* __restrict__ x, const float* __restrict__ W,
    const float* __restrict__ bias, const int* __restrict__ wsI,
    const float* __restrict__ wsF, float* __restrict__ dst) {
  __shared__ float xT[DIN][68];
  __shared__ float Wl[32][DOUT];
  __shared__ int   rowsl[64];
  __shared__ int   pl[64];
  __shared__ float wl[64];

  const int nwork = wsI[WS_NWORK];
  const int bid = blockIdx.x;
  if (bid >= nwork) return;
  const int wk = wsI[WS_WORK + bid];
  const int e = wk >> 16, t = wk & 0xffff;
  const int cnt = wsI[WS_COUNTS + e];
  const int srcb = wsI[WS_BASE + e] + t * 64;
  const int m = min(64, cnt - t * 64);
  const int tid = threadIdx.x;

  if (tid < 64) {
    int src = srcb + ((tid < m) ? tid : 0);  // clamp pad lanes
    rowsl[tid] = wsI[WS_PAIRROW + src];
    pl[tid]    = wsI[WS_PAIRP + src];
    wl[tid] = (tid < m) ? wsF[WS_PAIRW + srcb + tid] : 0.f;
  }
  __syncthreads();

  {
    int r = tid >> 2;
    int d0 = (tid & 3) * 32;
    const float* xr = x + (long)rowsl[r] * DIN + d0;
    #pragma unroll
    for (int k = 0; k < 32; k += 4) {
      float4 v = *(const float4*)(xr + k);
      xT[d0 + k + 0][r] = v.x;
      xT[d0 + k + 1][r] = v.y;
      xT[d0 + k + 2][r] = v.z;
      xT[d0 + k + 3][r] = v.w;
    }
  }

  float acc[4][8];
  #pragma unroll
  for (int i = 0; i < 4; ++i)
    #pragma unroll
    for (int j = 0; j < 8; ++j) acc[i][j] = 0.f;

  const int tr = tid & 15, tc = tid >> 4;

  for (int dc = 0; dc < DIN; dc += 32) {
    __syncthreads();
    const float4* Wg = (const float4*)(W + (long)e * DIN * DOUT + dc * DOUT);
    float4* Wl4 = (float4*)&Wl[0][0];
    #pragma unroll
    for (int k = 0; k < 4; ++k) Wl4[tid + k * 256] = Wg[tid + k * 256];
    __syncthreads();
    #pragma unroll 8
    for (int dd = 0; dd < 32; ++dd) {
      float4 xv = *(const float4*)&xT[dc + dd][tr * 4];
      float4 wa = *(const float4*)&Wl[dd][tc * 8];
      float4 wb = *(const float4*)&Wl[dd][tc * 8 + 4];
      float xs[4] = {xv.x, xv.y, xv.z, xv.w};
      float ws8[8] = {wa.x, wa.y, wa.z, wa.w, wb.x, wb.y, wb.z, wb.w};
      #pragma unroll
      for (int i = 0; i < 4; ++i)
        #pragma unroll
        for (int j = 0; j < 8; ++j) acc[i][j] += xs[i] * ws8[j];
    }
  }

  #pragma unroll
  for (int i = 0; i < 4; ++i) {
    int r = tr * 4 + i;
    if (r < m) {
      float w = wl[r];
      const float* bp = bias + (long)e * DOUT + tc * 8;
      if (SLOT) {
        float* op = dst + (long)pl[r] * DOUT + tc * 8;
        #pragma unroll
        for (int j = 0; j < 8; ++j) op[j] = w * (acc[i][j] + bp[j]);
      } else {
        float* op = dst + (long)rowsl[r] * DOUT + tc * 8;
        #pragma unroll
        for (int j = 0; j < 8; ++j) atomicAdd(&op[j], w * (acc[i][j] + bp[j]));
      }
    }
  }
}

// out[row] = slot[row*3] + slot[row*3+1] + slot[row*3+2]  (matches np pairwise
// order for 3 terms: (s0+s1)+s2)
__global__ __launch_bounds__(256) void k5_gather(const float* __restrict__ slot,
                                                 float* __restrict__ out) {
  int gid = blockIdx.x * 256 + threadIdx.x;   // NB*32 float4s
  int row = gid >> 5, c4 = gid & 31;
  const float4* s = (const float4*)(slot + (long)row * 3 * DOUT) + c4;
  float4 a = s[0], b = s[32], c = s[64];
  float4 o;
  o.x = (a.x + b.x) + c.x;
  o.y = (a.y + b.y) + c.y;
  o.z = (a.z + b.z) + c.z;
  o.w = (a.w + b.w) + c.w;
  ((float4*)out)[gid] = o;
}

extern "C" void kernel_launch(void* const* d_in, const int* in_sizes, int n_in,
                              void* d_out, int out_size, void* d_ws, size_t ws_size,
                              hipStream_t stream) {
  const float* x    = (const float*)d_in[0];
  const float* dsc  = (const float*)d_in[1];
  const float* cent = (const float*)d_in[2];
  const float* W    = (const float*)d_in[3];
  const float* bias = (const float*)d_in[4];
  float* out = (float*)d_out;
  int* wsI = (int*)d_ws;
  float* wsF = (float*)d_ws;

  const size_t need = ((size_t)WS_SLOT + (size_t)3 * NB * DOUT) * 4;
  const int useSlot = (ws_size >= need) ? 1 : 0;   // constant across calls

  hipLaunchKernelGGL(k0_init,    dim3(1),            dim3(64),  0, stream, wsI);
  hipLaunchKernelGGL(k1_route,   dim3(NB / 16),      dim3(256), 0, stream,
                     x, dsc, cent, out, wsI, wsF, useSlot ? 0 : 1);
  hipLaunchKernelGGL(k2_scan,    dim3(1),            dim3(64),  0, stream, wsI);
  hipLaunchKernelGGL(k3_scatter, dim3(3 * NB / 256), dim3(256), 0, stream, wsI, wsF);
  if (useSlot) {
    float* slot = (float*)d_ws + WS_SLOT;
    hipLaunchKernelGGL(k4_gemm<1>, dim3(MAX_WORK),   dim3(256), 0, stream,
                       x, W, bias, wsI, wsF, slot);
    hipLaunchKernelGGL(k5_gather,  dim3(NB * 32 / 256), dim3(256), 0, stream, slot, out);
  } else {
    hipLaunchKernelGGL(k4_gemm<0>, dim3(MAX_WORK),   dim3(256), 0, stream,
                       x, W, bias, wsI, wsF, out);
  }
}

// Round 5
// 371.266 us; speedup vs baseline: 1.4648x; 1.0003x over previous
//
#include <hip/hip_runtime.h>
#include <hip/hip_bf16.h>

#define NB   16384
#define NE   64
#define DIN  128
#define DOUT 128

// ws layout in 4-byte words
#define WS_COUNTS   0        // 64
#define WS_BASE     64       // 64
#define WS_CURSOR   128      // 64
#define WS_NWORK    192      // 1
#define WS_WORK     256      // <= 832
#define WS_PICKED   2048     // 3*NB
#define WS_PW       51200    // 3*NB
#define WS_PAIRROW  100352   // 3*NB
#define WS_PAIRW    149504   // 3*NB
#define WS_PAIRP    198656   // 3*NB  (pair index p = row*3+slot, for slot path)
#define WS_SLOT     247808   // 3*NB*128 floats (slot buffer, slot path only)
#define MAX_WORK    832      // sum_e ceil(n_e/64) <= 3*NB/64 + 63 < 832

__global__ __launch_bounds__(64) void k0_init(int* __restrict__ wsI) {
  if (threadIdx.x < NE) wsI[WS_COUNTS + threadIdx.x] = 0;
}

__global__ __launch_bounds__(256) void k1_route(
    const float* __restrict__ x, const float* __restrict__ dsc,
    const float* __restrict__ cent, float* __restrict__ out,
    int* __restrict__ wsI, float* __restrict__ wsF, int zero_out) {
  __shared__ float cl[NE][132];
  __shared__ float xl[16][132];
  __shared__ float dl[4][64];   // per-wave dist row; stride 256B keeps f4 aligned
  const int tid = threadIdx.x;
  const int row0 = blockIdx.x * 16;

  const float4* c4 = (const float4*)cent;
  #pragma unroll
  for (int k = 0; k < 8; ++k) {
    int idx = tid + k * 256;
    int e = idx >> 5, dc = idx & 31;
    *(float4*)&cl[e][dc * 4] = c4[idx];
  }
  const float4* x4 = (const float4*)x + row0 * 32;
  #pragma unroll
  for (int k = 0; k < 2; ++k) {
    int idx = tid + k * 256;
    int r = idx >> 5, dc = idx & 31;
    *(float4*)&xl[r][dc * 4] = x4[idx];
  }
  if (zero_out) {  // atomic-fallback path only
    float4* o4 = (float4*)out + row0 * 32;
    float4 z; z.x = z.y = z.z = z.w = 0.f;
    #pragma unroll
    for (int k = 0; k < 2; ++k) o4[tid + k * 256] = z;
  }
  __syncthreads();

  const int lane = tid & 63, wv = tid >> 6;
  const float ds = dsc[0];

  for (int rr = wv; rr < 16; rr += 4) {
    // distance_sq for expert `lane`, replicating numpy pairwise mean over 128:
    // 8 accumulators r[j] += sq[8i+j], then ((r0+r1)+(r2+r3))+((r4+r5)+(r6+r7))
    float4 r0 = {0.f, 0.f, 0.f, 0.f}, r1 = {0.f, 0.f, 0.f, 0.f};
    {
      #pragma clang fp contract(off)
      for (int i = 0; i < 16; ++i) {
        float4 xa = *(const float4*)&xl[rr][i * 8];
        float4 xb = *(const float4*)&xl[rr][i * 8 + 4];
        float4 ca = *(const float4*)&cl[lane][i * 8];
        float4 cb = *(const float4*)&cl[lane][i * 8 + 4];
        float t0 = ds * (xa.x - ca.x), t1 = ds * (xa.y - ca.y);
        float t2 = ds * (xa.z - ca.z), t3 = ds * (xa.w - ca.w);
        float u0 = ds * (xb.x - cb.x), u1 = ds * (xb.y - cb.y);
        float u2 = ds * (xb.z - cb.z), u3 = ds * (xb.w - cb.w);
        r0.x += t0 * t0; r0.y += t1 * t1; r0.z += t2 * t2; r0.w += t3 * t3;
        r1.x += u0 * u0; r1.y += u1 * u1; r1.z += u2 * u2; r1.w += u3 * u3;
      }
    }
    float s = ((r0.x + r0.y) + (r0.z + r0.w)) + ((r1.x + r1.y) + (r1.z + r1.w));
    float dist = s / 128.0f;

    // rank-based top-3 (replaces 36-deep bpermute butterfly chain, which was
    // the 184us latency wall): each lane's rank = #experts strictly ahead of
    // it under (dist, index) lexicographic order == jax top_k tie rule.
    dl[wv][lane] = dist;
    int rank = 0;
    #pragma unroll
    for (int j = 0; j < 64; j += 8) {
      float4 da = *(const float4*)&dl[wv][j];      // uniform addr -> broadcast
      float4 db = *(const float4*)&dl[wv][j + 4];
      rank += (da.x < dist || (da.x == dist && (j + 0) < lane)) ? 1 : 0;
      rank += (da.y < dist || (da.y == dist && (j + 1) < lane)) ? 1 : 0;
      rank += (da.z < dist || (da.z == dist && (j + 2) < lane)) ? 1 : 0;
      rank += (da.w < dist || (da.w == dist && (j + 3) < lane)) ? 1 : 0;
      rank += (db.x < dist || (db.x == dist && (j + 4) < lane)) ? 1 : 0;
      rank += (db.y < dist || (db.y == dist && (j + 5) < lane)) ? 1 : 0;
      rank += (db.z < dist || (db.z == dist && (j + 6) < lane)) ? 1 : 0;
      rank += (db.w < dist || (db.w == dist && (j + 7) < lane)) ? 1 : 0;
    }
    unsigned long long m0 = __ballot(rank == 0);
    unsigned long long m1 = __ballot(rank == 1);
    unsigned long long m2 = __ballot(rank == 2);
    int i0 = __ffsll(m0) - 1;
    int i1 = __ffsll(m1) - 1;
    int i2 = __ffsll(m2) - 1;

    // weights from experts 0,1,2 distances (reference quirk: [:, :es])
    float d0 = dl[wv][0], d1 = dl[wv][1], d2 = dl[wv][2];
    float w0 = 1.f / (1.f + d0), w1 = 1.f / (1.f + d1), w2 = 1.f / (1.f + d2);
    float sw = (w0 + w1) + w2;
    w0 /= sw; w1 /= sw; w2 /= sw;

    int row = row0 + rr;
    if (lane < 3) {
      float w = (lane == 0) ? w0 : ((lane == 1) ? w1 : w2);
      int p = (lane == 0) ? i0 : ((lane == 1) ? i1 : i2);
      wsI[WS_PICKED + row * 3 + lane] = p;
      wsF[WS_PW + row * 3 + lane] = w;
      atomicAdd(&wsI[WS_COUNTS + p], 1);
    }
  }
}

// 1-wave parallel scan
__global__ __launch_bounds__(64) void k2_scan(int* __restrict__ wsI) {
  const int lane = threadIdx.x;
  int cnt = wsI[WS_COUNTS + lane];
  int xs = cnt;
  #pragma unroll
  for (int off = 1; off < 64; off <<= 1) {
    int y = __shfl_up(xs, off, 64);
    if (lane >= off) xs += y;
  }
  int excl = xs - cnt;
  wsI[WS_BASE + lane]   = excl;
  wsI[WS_CURSOR + lane] = excl;
  int nt = (cnt + 63) >> 6;
  int ts = nt;
  #pragma unroll
  for (int off = 1; off < 64; off <<= 1) {
    int y = __shfl_up(ts, off, 64);
    if (lane >= off) ts += y;
  }
  int texcl = ts - nt;
  for (int t = 0; t < nt; ++t) wsI[WS_WORK + texcl + t] = (lane << 16) | t;
  if (lane == 63) wsI[WS_NWORK] = ts;
}

__global__ __launch_bounds__(256) void k3_scatter(int* __restrict__ wsI,
                                                  float* __restrict__ wsF) {
  int p = blockIdx.x * 256 + threadIdx.x;
  if (p < 3 * NB) {
    int e = wsI[WS_PICKED + p];
    float w = wsF[WS_PW + p];
    int pos = atomicAdd(&wsI[WS_CURSOR + e], 1);
    wsI[WS_PAIRROW + pos] = p / 3;   // row (for x gather)
    wsI[WS_PAIRP + pos]   = p;       // pair index (for slot write)
    wsF[WS_PAIRW + pos]   = w;
  }
}

// One block per (expert, 64-row tile). SLOT=1: write weighted result to
// slotbuf[p] (atomic-free). SLOT=0: atomicAdd into out (fallback).
template <int SLOT>
__global__ __launch_bounds__(256) void k4_gemm(
    const float* __restrict__ x, const float* __restrict__ W,
    const float* __restrict__ bias, const int* __restrict__ wsI,
    const float* __restrict__ wsF, float* __restrict__ dst) {
  __shared__ float xT[DIN][68];
  __shared__ float Wl[32][DOUT];
  __shared__ int   rowsl[64];
  __shared__ int   pl[64];
  __shared__ float wl[64];

  const int nwork = wsI[WS_NWORK];
  const int bid = blockIdx.x;
  if (bid >= nwork) return;
  const int wk = wsI[WS_WORK + bid];
  const int e = wk >> 16, t = wk & 0xffff;
  const int cnt = wsI[WS_COUNTS + e];
  const int srcb = wsI[WS_BASE + e] + t * 64;
  const int m = min(64, cnt - t * 64);
  const int tid = threadIdx.x;

  if (tid < 64) {
    int src = srcb + ((tid < m) ? tid : 0);  // clamp pad lanes
    rowsl[tid] = wsI[WS_PAIRROW + src];
    pl[tid]    = wsI[WS_PAIRP + src];
    wl[tid] = (tid < m) ? wsF[WS_PAIRW + srcb + tid] : 0.f;
  }
  __syncthreads();

  {
    int r = tid >> 2;
    int d0 = (tid & 3) * 32;
    const float* xr = x + (long)rowsl[r] * DIN + d0;
    #pragma unroll
    for (int k = 0; k < 32; k += 4) {
      float4 v = *(const float4*)(xr + k);
      xT[d0 + k + 0][r] = v.x;
      xT[d0 + k + 1][r] = v.y;
      xT[d0 + k + 2][r] = v.z;
      xT[d0 + k + 3][r] = v.w;
    }
  }

  float acc[4][8];
  #pragma unroll
  for (int i = 0; i < 4; ++i)
    #pragma unroll
    for (int j = 0; j < 8; ++j) acc[i][j] = 0.f;

  const int tr = tid & 15, tc = tid >> 4;

  for (int dc = 0; dc < DIN; dc += 32) {
    __syncthreads();
    const float4* Wg = (const float4*)(W + (long)e * DIN * DOUT + dc * DOUT);
    float4* Wl4 = (float4*)&Wl[0][0];
    #pragma unroll
    for (int k = 0; k < 4; ++k) Wl4[tid + k * 256] = Wg[tid + k * 256];
    __syncthreads();
    #pragma unroll 8
    for (int dd = 0; dd < 32; ++dd) {
      float4 xv = *(const float4*)&xT[dc + dd][tr * 4];
      float4 wa = *(const float4*)&Wl[dd][tc * 8];
      float4 wb = *(const float4*)&Wl[dd][tc * 8 + 4];
      float xs[4] = {xv.x, xv.y, xv.z, xv.w};
      float ws8[8] = {wa.x, wa.y, wa.z, wa.w, wb.x, wb.y, wb.z, wb.w};
      #pragma unroll
      for (int i = 0; i < 4; ++i)
        #pragma unroll
        for (int j = 0; j < 8; ++j) acc[i][j] += xs[i] * ws8[j];
    }
  }

  #pragma unroll
  for (int i = 0; i < 4; ++i) {
    int r = tr * 4 + i;
    if (r < m) {
      float w = wl[r];
      const float* bp = bias + (long)e * DOUT + tc * 8;
      if (SLOT) {
        float* op = dst + (long)pl[r] * DOUT + tc * 8;
        #pragma unroll
        for (int j = 0; j < 8; ++j) op[j] = w * (acc[i][j] + bp[j]);
      } else {
        float* op = dst + (long)rowsl[r] * DOUT + tc * 8;
        #pragma unroll
        for (int j = 0; j < 8; ++j) atomicAdd(&op[j], w * (acc[i][j] + bp[j]));
      }
    }
  }
}

// out[row] = (slot[row*3] + slot[row*3+1]) + slot[row*3+2]
__global__ __launch_bounds__(256) void k5_gather(const float* __restrict__ slot,
                                                 float* __restrict__ out) {
  int gid = blockIdx.x * 256 + threadIdx.x;   // NB*32 float4s
  int row = gid >> 5, c4 = gid & 31;
  const float4* s = (const float4*)(slot + (long)row * 3 * DOUT) + c4;
  float4 a = s[0], b = s[32], c = s[64];
  float4 o;
  o.x = (a.x + b.x) + c.x;
  o.y = (a.y + b.y) + c.y;
  o.z = (a.z + b.z) + c.z;
  o.w = (a.w + b.w) + c.w;
  ((float4*)out)[gid] = o;
}

extern "C" void kernel_launch(void* const* d_in, const int* in_sizes, int n_in,
                              void* d_out, int out_size, void* d_ws, size_t ws_size,
                              hipStream_t stream) {
  const float* x    = (const float*)d_in[0];
  const float* dsc  = (const float*)d_in[1];
  const float* cent = (const float*)d_in[2];
  const float* W    = (const float*)d_in[3];
  const float* bias = (const float*)d_in[4];
  float* out = (float*)d_out;
  int* wsI = (int*)d_ws;
  float* wsF = (float*)d_ws;

  const size_t need = ((size_t)WS_SLOT + (size_t)3 * NB * DOUT) * 4;
  const int useSlot = (ws_size >= need) ? 1 : 0;   // constant across calls

  hipLaunchKernelGGL(k0_init,    dim3(1),            dim3(64),  0, stream, wsI);
  hipLaunchKernelGGL(k1_route,   dim3(NB / 16),      dim3(256), 0, stream,
                     x, dsc, cent, out, wsI, wsF, useSlot ? 0 : 1);
  hipLaunchKernelGGL(k2_scan,    dim3(1),            dim3(64),  0, stream, wsI);
  hipLaunchKernelGGL(k3_scatter, dim3(3 * NB / 256), dim3(256), 0, stream, wsI, wsF);
  if (useSlot) {
    float* slot = (float*)d_ws + WS_SLOT;
    hipLaunchKernelGGL(k4_gemm<1>, dim3(MAX_WORK),   dim3(256), 0, stream,
                       x, W, bias, wsI, wsF, slot);
    hipLaunchKernelGGL(k5_gather,  dim3(NB * 32 / 256), dim3(256), 0, stream, slot, out);
  } else {
    hipLaunchKernelGGL(k4_gemm<0>, dim3(MAX_WORK),   dim3(256), 0, stream,
                       x, W, bias, wsI, wsF, out);
  }
}

// Round 6
// 155.110 us; speedup vs baseline: 3.5061x; 2.3936x over previous
//
#include <hip/hip_runtime.h>
#include <hip/hip_bf16.h>

#define NB   16384
#define NE   64
#define DIN  128
#define DOUT 128
#define CPAD 32   // pad atomic counters to 128B (own cache line) — contention fix

// ws layout in 4-byte words
#define WS_COUNTS   0         // 64*CPAD
#define WS_CURSOR   2048      // 64*CPAD
#define WS_BASE     4096      // 64
#define WS_NWORK    4160      // 1
#define WS_WORK     4224      // <= 832
#define WS_PICKED   8192      // 3*NB
#define WS_PW       57344     // 3*NB
#define WS_PAIRROW  106496    // 3*NB
#define WS_PAIRW    155648    // 3*NB
#define WS_PAIRP    204800    // 3*NB  (pair index p = row*3+slot, for slot path)
#define WS_SLOT     253952    // 3*NB*128 floats (slot buffer, slot path only)
#define MAX_WORK    832       // sum_e ceil(n_e/64) <= 3*NB/64 + 63 < 832

__global__ __launch_bounds__(64) void k0_init(int* __restrict__ wsI) {
  if (threadIdx.x < NE) wsI[WS_COUNTS + threadIdx.x * CPAD] = 0;
}

__global__ __launch_bounds__(256) void k1_route(
    const float* __restrict__ x, const float* __restrict__ dsc,
    const float* __restrict__ cent, float* __restrict__ out,
    int* __restrict__ wsI, float* __restrict__ wsF, int zero_out) {
  __shared__ float cl[NE][132];
  __shared__ float xl[16][132];
  __shared__ float dl[4][64];   // per-wave dist row
  const int tid = threadIdx.x;
  const int row0 = blockIdx.x * 16;

  const float4* c4 = (const float4*)cent;
  #pragma unroll
  for (int k = 0; k < 8; ++k) {
    int idx = tid + k * 256;
    int e = idx >> 5, dc = idx & 31;
    *(float4*)&cl[e][dc * 4] = c4[idx];
  }
  const float4* x4 = (const float4*)x + row0 * 32;
  #pragma unroll
  for (int k = 0; k < 2; ++k) {
    int idx = tid + k * 256;
    int r = idx >> 5, dc = idx & 31;
    *(float4*)&xl[r][dc * 4] = x4[idx];
  }
  if (zero_out) {  // atomic-fallback path only
    float4* o4 = (float4*)out + row0 * 32;
    float4 z; z.x = z.y = z.z = z.w = 0.f;
    #pragma unroll
    for (int k = 0; k < 2; ++k) o4[tid + k * 256] = z;
  }
  __syncthreads();

  const int lane = tid & 63, wv = tid >> 6;
  const float ds = dsc[0];

  for (int rr = wv; rr < 16; rr += 4) {
    // distance_sq for expert `lane`, replicating numpy pairwise mean over 128:
    // 8 accumulators r[j] += sq[8i+j], then ((r0+r1)+(r2+r3))+((r4+r5)+(r6+r7))
    float4 r0 = {0.f, 0.f, 0.f, 0.f}, r1 = {0.f, 0.f, 0.f, 0.f};
    {
      #pragma clang fp contract(off)
      for (int i = 0; i < 16; ++i) {
        float4 xa = *(const float4*)&xl[rr][i * 8];
        float4 xb = *(const float4*)&xl[rr][i * 8 + 4];
        float4 ca = *(const float4*)&cl[lane][i * 8];
        float4 cb = *(const float4*)&cl[lane][i * 8 + 4];
        float t0 = ds * (xa.x - ca.x), t1 = ds * (xa.y - ca.y);
        float t2 = ds * (xa.z - ca.z), t3 = ds * (xa.w - ca.w);
        float u0 = ds * (xb.x - cb.x), u1 = ds * (xb.y - cb.y);
        float u2 = ds * (xb.z - cb.z), u3 = ds * (xb.w - cb.w);
        r0.x += t0 * t0; r0.y += t1 * t1; r0.z += t2 * t2; r0.w += t3 * t3;
        r1.x += u0 * u0; r1.y += u1 * u1; r1.z += u2 * u2; r1.w += u3 * u3;
      }
    }
    float s = ((r0.x + r0.y) + (r0.z + r0.w)) + ((r1.x + r1.y) + (r1.z + r1.w));
    float dist = s / 128.0f;

    // rank-based top-3: rank = #experts ahead under (dist, index) lex order
    // == jax top_k tie rule (lower index wins ties)
    dl[wv][lane] = dist;
    int rank = 0;
    #pragma unroll
    for (int j = 0; j < 64; j += 8) {
      float4 da = *(const float4*)&dl[wv][j];      // uniform addr -> broadcast
      float4 db = *(const float4*)&dl[wv][j + 4];
      rank += (da.x < dist || (da.x == dist && (j + 0) < lane)) ? 1 : 0;
      rank += (da.y < dist || (da.y == dist && (j + 1) < lane)) ? 1 : 0;
      rank += (da.z < dist || (da.z == dist && (j + 2) < lane)) ? 1 : 0;
      rank += (da.w < dist || (da.w == dist && (j + 3) < lane)) ? 1 : 0;
      rank += (db.x < dist || (db.x == dist && (j + 4) < lane)) ? 1 : 0;
      rank += (db.y < dist || (db.y == dist && (j + 5) < lane)) ? 1 : 0;
      rank += (db.z < dist || (db.z == dist && (j + 6) < lane)) ? 1 : 0;
      rank += (db.w < dist || (db.w == dist && (j + 7) < lane)) ? 1 : 0;
    }
    unsigned long long m0 = __ballot(rank == 0);
    unsigned long long m1 = __ballot(rank == 1);
    unsigned long long m2 = __ballot(rank == 2);
    int i0 = __ffsll(m0) - 1;
    int i1 = __ffsll(m1) - 1;
    int i2 = __ffsll(m2) - 1;

    // weights from experts 0,1,2 distances (reference quirk: [:, :es])
    float d0 = dl[wv][0], d1 = dl[wv][1], d2 = dl[wv][2];
    float w0 = 1.f / (1.f + d0), w1 = 1.f / (1.f + d1), w2 = 1.f / (1.f + d2);
    float sw = (w0 + w1) + w2;
    w0 /= sw; w1 /= sw; w2 /= sw;

    int row = row0 + rr;
    if (lane < 3) {
      float w = (lane == 0) ? w0 : ((lane == 1) ? w1 : w2);
      int p = (lane == 0) ? i0 : ((lane == 1) ? i1 : i2);
      wsI[WS_PICKED + row * 3 + lane] = p;
      wsF[WS_PW + row * 3 + lane] = w;
      atomicAdd(&wsI[WS_COUNTS + p * CPAD], 1);   // padded: own cache line
    }
  }
}

// 1-wave parallel scan
__global__ __launch_bounds__(64) void k2_scan(int* __restrict__ wsI) {
  const int lane = threadIdx.x;
  int cnt = wsI[WS_COUNTS + lane * CPAD];
  int xs = cnt;
  #pragma unroll
  for (int off = 1; off < 64; off <<= 1) {
    int y = __shfl_up(xs, off, 64);
    if (lane >= off) xs += y;
  }
  int excl = xs - cnt;
  wsI[WS_BASE + lane] = excl;
  wsI[WS_CURSOR + lane * CPAD] = excl;
  int nt = (cnt + 63) >> 6;
  int ts = nt;
  #pragma unroll
  for (int off = 1; off < 64; off <<= 1) {
    int y = __shfl_up(ts, off, 64);
    if (lane >= off) ts += y;
  }
  int texcl = ts - nt;
  for (int t = 0; t < nt; ++t) wsI[WS_WORK + texcl + t] = (lane << 16) | t;
  if (lane == 63) wsI[WS_NWORK] = ts;
}

__global__ __launch_bounds__(256) void k3_scatter(int* __restrict__ wsI,
                                                  float* __restrict__ wsF) {
  int p = blockIdx.x * 256 + threadIdx.x;
  if (p < 3 * NB) {
    int e = wsI[WS_PICKED + p];
    float w = wsF[WS_PW + p];
    int pos = atomicAdd(&wsI[WS_CURSOR + e * CPAD], 1);  // padded
    wsI[WS_PAIRROW + pos] = p / 3;   // row (for x gather)
    wsI[WS_PAIRP + pos]   = p;       // pair index (for slot write)
    wsF[WS_PAIRW + pos]   = w;
  }
}

// One block per (expert, 64-row tile). SLOT=1: write weighted result to
// slotbuf[p] (atomic-free). SLOT=0: atomicAdd into out (fallback).
template <int SLOT>
__global__ __launch_bounds__(256) void k4_gemm(
    const float* __restrict__ x, const float* __restrict__ W,
    const float* __restrict__ bias, const int* __restrict__ wsI,
    const float* __restrict__ wsF, float* __restrict__ dst) {
  __shared__ float xT[DIN][68];
  __shared__ float Wl[32][DOUT];
  __shared__ int   rowsl[64];
  __shared__ int   pl[64];
  __shared__ float wl[64];

  const int nwork = wsI[WS_NWORK];
  const int bid = blockIdx.x;
  if (bid >= nwork) return;
  const int wk = wsI[WS_WORK + bid];
  const int e = wk >> 16, t = wk & 0xffff;
  const int cnt = wsI[WS_COUNTS + e * CPAD];
  const int srcb = wsI[WS_BASE + e] + t * 64;
  const int m = min(64, cnt - t * 64);
  const int tid = threadIdx.x;

  if (tid < 64) {
    int src = srcb + ((tid < m) ? tid : 0);  // clamp pad lanes
    rowsl[tid] = wsI[WS_PAIRROW + src];
    pl[tid]    = wsI[WS_PAIRP + src];
    wl[tid] = (tid < m) ? wsF[WS_PAIRW + srcb + tid] : 0.f;
  }
  __syncthreads();

  {
    int r = tid >> 2;
    int d0 = (tid & 3) * 32;
    const float* xr = x + (long)rowsl[r] * DIN + d0;
    #pragma unroll
    for (int k = 0; k < 32; k += 4) {
      float4 v = *(const float4*)(xr + k);
      xT[d0 + k + 0][r] = v.x;
      xT[d0 + k + 1][r] = v.y;
      xT[d0 + k + 2][r] = v.z;
      xT[d0 + k + 3][r] = v.w;
    }
  }

  float acc[4][8];
  #pragma unroll
  for (int i = 0; i < 4; ++i)
    #pragma unroll
    for (int j = 0; j < 8; ++j) acc[i][j] = 0.f;

  const int tr = tid & 15, tc = tid >> 4;

  for (int dc = 0; dc < DIN; dc += 32) {
    __syncthreads();
    const float4* Wg = (const float4*)(W + (long)e * DIN * DOUT + dc * DOUT);
    float4* Wl4 = (float4*)&Wl[0][0];
    #pragma unroll
    for (int k = 0; k < 4; ++k) Wl4[tid + k * 256] = Wg[tid + k * 256];
    __syncthreads();
    #pragma unroll 8
    for (int dd = 0; dd < 32; ++dd) {
      float4 xv = *(const float4*)&xT[dc + dd][tr * 4];
      float4 wa = *(const float4*)&Wl[dd][tc * 8];
      float4 wb = *(const float4*)&Wl[dd][tc * 8 + 4];
      float xs[4] = {xv.x, xv.y, xv.z, xv.w};
      float ws8[8] = {wa.x, wa.y, wa.z, wa.w, wb.x, wb.y, wb.z, wb.w};
      #pragma unroll
      for (int i = 0; i < 4; ++i)
        #pragma unroll
        for (int j = 0; j < 8; ++j) acc[i][j] += xs[i] * ws8[j];
    }
  }

  #pragma unroll
  for (int i = 0; i < 4; ++i) {
    int r = tr * 4 + i;
    if (r < m) {
      float w = wl[r];
      const float* bp = bias + (long)e * DOUT + tc * 8;
      if (SLOT) {
        float* op = dst + (long)pl[r] * DOUT + tc * 8;
        #pragma unroll
        for (int j = 0; j < 8; ++j) op[j] = w * (acc[i][j] + bp[j]);
      } else {
        float* op = dst + (long)rowsl[r] * DOUT + tc * 8;
        #pragma unroll
        for (int j = 0; j < 8; ++j) atomicAdd(&op[j], w * (acc[i][j] + bp[j]));
      }
    }
  }
}

// out[row] = (slot[row*3] + slot[row*3+1]) + slot[row*3+2]
__global__ __launch_bounds__(256) void k5_gather(const float* __restrict__ slot,
                                                 float* __restrict__ out) {
  int gid = blockIdx.x * 256 + threadIdx.x;   // NB*32 float4s
  int row = gid >> 5, c4 = gid & 31;
  const float4* s = (const float4*)(slot + (long)row * 3 * DOUT) + c4;
  float4 a = s[0], b = s[32], c = s[64];
  float4 o;
  o.x = (a.x + b.x) + c.x;
  o.y = (a.y + b.y) + c.y;
  o.z = (a.z + b.z) + c.z;
  o.w = (a.w + b.w) + c.w;
  ((float4*)out)[gid] = o;
}

extern "C" void kernel_launch(void* const* d_in, const int* in_sizes, int n_in,
                              void* d_out, int out_size, void* d_ws, size_t ws_size,
                              hipStream_t stream) {
  const float* x    = (const float*)d_in[0];
  const float* dsc  = (const float*)d_in[1];
  const float* cent = (const float*)d_in[2];
  const float* W    = (const float*)d_in[3];
  const float* bias = (const float*)d_in[4];
  float* out = (float*)d_out;
  int* wsI = (int*)d_ws;
  float* wsF = (float*)d_ws;

  const size_t need = ((size_t)WS_SLOT + (size_t)3 * NB * DOUT) * 4;
  const int useSlot = (ws_size >= need) ? 1 : 0;   // constant across calls

  hipLaunchKernelGGL(k0_init,    dim3(1),            dim3(64),  0, stream, wsI);
  hipLaunchKernelGGL(k1_route,   dim3(NB / 16),      dim3(256), 0, stream,
                     x, dsc, cent, out, wsI, wsF, useSlot ? 0 : 1);
  hipLaunchKernelGGL(k2_scan,    dim3(1),            dim3(64),  0, stream, wsI);
  hipLaunchKernelGGL(k3_scatter, dim3(3 * NB / 256), dim3(256), 0, stream, wsI, wsF);
  if (useSlot) {
    float* slot = (float*)d_ws + WS_SLOT;
    hipLaunchKernelGGL(k4_gemm<1>, dim3(MAX_WORK),   dim3(256), 0, stream,
                       x, W, bias, wsI, wsF, slot);
    hipLaunchKernelGGL(k5_gather,  dim3(NB * 32 / 256), dim3(256), 0, stream, slot, out);
  } else {
    hipLaunchKernelGGL(k4_gemm<0>, dim3(MAX_WORK),   dim3(256), 0, stream,
                       x, W, bias, wsI, wsF, out);
  }
}